// Round 1
// baseline (1238.668 us; speedup 1.0000x reference)
//
#include <hip/hip_runtime.h>
#include <stdint.h>

// SNN forward: conv1+spike -> pool1+spike -> conv2+spike -> pool2+spike ->
// conv3+spike -> fc+spike, each with delay_shift between layers.
// Neuron: u = 0.75u + x; v = 0.96875v + u; s = (v>=100); v *= (1-s).
// Intermediate spikes as uint8 in d_ws. ws requirement ~108.2 MB.

#define T 128
#define AI 0.75f
#define AV 0.96875f
#define THETA 100.0f

__device__ __forceinline__ void neuron_step(float x, float& u, float& v, float& s) {
    u = AI * u + x;
    v = AV * v + u;
    s = (v >= THETA) ? 1.0f : 0.0f;
    v = v * (1.0f - s);
}

// ---------------- conv1 (2->8, 40x40) fused with neuron scan ----------------
// in: [16][2][40][40][128] float, w: [8][2][3][3] (x20), out: [16][8][40][40][128] u8
__global__ __launch_bounds__(256) void conv1_spike(
    const float* __restrict__ in, const float* __restrict__ cw,
    uint8_t* __restrict__ out)
{
    __shared__ float wsm[8 * 2 * 9];
    if (threadIdx.x < 144) wsm[threadIdx.x] = cw[threadIdx.x] * 20.0f;
    __syncthreads();

    int id = blockIdx.x * 256 + threadIdx.x;          // 204,800 total
    int wx = id % 40;
    int hy = (id / 40) % 40;
    int o  = (id / 1600) % 8;
    int n  = id / 12800;

    const float* p[18];
    float wt[18];
    int k = 0;
    #pragma unroll
    for (int c = 0; c < 2; c++)
      #pragma unroll
      for (int dh = -1; dh <= 1; dh++)
        #pragma unroll
        for (int dw = -1; dw <= 1; dw++) {
            int hh = hy + dh, ww = wx + dw;
            bool ok = (hh >= 0) && (hh < 40) && (ww >= 0) && (ww < 40);
            int hc = ok ? hh : hy, wc = ok ? ww : wx;
            p[k]  = in + (((n * 2 + c) * 40 + hc) * 40 + wc) * T;
            wt[k] = ok ? wsm[(o * 2 + c) * 9 + (dh + 1) * 3 + (dw + 1)] : 0.0f;
            k++;
        }

    uint8_t* op = out + (((n * 8 + o) * 40 + hy) * 40 + wx) * T;
    float u = 0.f, v = 0.f;
    for (int tb = 0; tb < T / 4; tb++) {
        float ax = 0.f, ay = 0.f, az = 0.f, aw = 0.f;
        #pragma unroll
        for (int q = 0; q < 18; q++) {
            float4 xv = *(const float4*)(p[q] + tb * 4);
            ax += wt[q] * xv.x; ay += wt[q] * xv.y;
            az += wt[q] * xv.z; aw += wt[q] * xv.w;
        }
        float s0, s1, s2, s3;
        neuron_step(ax, u, v, s0); neuron_step(ay, u, v, s1);
        neuron_step(az, u, v, s2); neuron_step(aw, u, v, s3);
        *(uchar4*)(op + tb * 4) =
            make_uchar4((unsigned char)s0, (unsigned char)s1,
                        (unsigned char)s2, (unsigned char)s3);
    }
}

// ---------------- sum-pool 2x2 (*pw) on DELAYED spikes, fused scan ----------
// in: [16][C][2HO][2WO][T] u8, out: [16][C][HO][WO][T] u8
template<int C, int HO, int WO>
__global__ __launch_bounds__(256) void pool_spike(
    const uint8_t* __restrict__ in, const float* __restrict__ pw_ptr,
    uint8_t* __restrict__ out)
{
    int id = blockIdx.x * 256 + threadIdx.x;          // N*C*HO*WO
    int wx = id % WO;
    int hy = (id / WO) % HO;
    int c  = (id / (WO * HO)) % C;
    int n  = id / (WO * HO * C);
    float pw = pw_ptr[0];

    const uint8_t* p00 = in + (((n * C + c) * (2 * HO) + 2 * hy) * (2 * WO) + 2 * wx) * T;
    const uint8_t* p01 = p00 + T;
    const uint8_t* p10 = p00 + 2 * WO * T;
    const uint8_t* p11 = p10 + T;
    uint8_t* op = out + (((n * C + c) * HO + hy) * WO + wx) * T;

    float u = 0.f, v = 0.f;
    int prev = 0;  // pooled sum at t-1 (delay_shift)
    for (int tb = 0; tb < T / 4; tb++) {
        uchar4 a = *(const uchar4*)(p00 + tb * 4);
        uchar4 b = *(const uchar4*)(p01 + tb * 4);
        uchar4 cc = *(const uchar4*)(p10 + tb * 4);
        uchar4 d = *(const uchar4*)(p11 + tb * 4);
        int s1i = a.x + b.x + cc.x + d.x;
        int s2i = a.y + b.y + cc.y + d.y;
        int s3i = a.z + b.z + cc.z + d.z;
        float s0, s1, s2, s3;
        neuron_step(pw * (float)prev, u, v, s0);
        neuron_step(pw * (float)s1i,  u, v, s1);
        neuron_step(pw * (float)s2i,  u, v, s2);
        neuron_step(pw * (float)s3i,  u, v, s3);
        prev = a.w + b.w + cc.w + d.w;
        *(uchar4*)(op + tb * 4) =
            make_uchar4((unsigned char)s0, (unsigned char)s1,
                        (unsigned char)s2, (unsigned char)s3);
    }
}

// ---------------- conv phase A: x[n][o][h][w][t] from DELAYED u8 spikes -----
// Fully parallel over (n,o,h,w,t). 256 | W*T*H guarantees per-block uniform o.
template<int CIN, int H, int W>
__global__ __launch_bounds__(256) void conv_x(
    const uint8_t* __restrict__ in, const float* __restrict__ cw, float scale,
    float* __restrict__ xout, int COUT)
{
    __shared__ float wsm[CIN * 9];
    int gid = blockIdx.x * 256 + threadIdx.x;
    int t  = gid % T;
    int wx = (gid / T) % W;
    int hy = (gid / (T * W)) % H;
    int o  = (gid / (T * W * H)) % COUT;
    int n  = gid / (T * W * H * COUT);
    if (threadIdx.x < CIN * 9) wsm[threadIdx.x] = cw[o * CIN * 9 + threadIdx.x] * scale;
    __syncthreads();

    int tm = (t == 0) ? 0 : (t - 1);                  // delay_shift
    float tmask = (t == 0) ? 0.0f : 1.0f;
    const uint8_t* base = in + ((n * CIN * H + hy) * W + wx) * T + tm;

    float x = 0.f;
    #pragma unroll
    for (int c = 0; c < CIN; c++) {
        #pragma unroll
        for (int dh = -1; dh <= 1; dh++) {
            #pragma unroll
            for (int dw = -1; dw <= 1; dw++) {
                bool ok = (hy + dh >= 0) && (hy + dh < H) &&
                          (wx + dw >= 0) && (wx + dw < W);
                float wv = ok ? wsm[c * 9 + (dh + 1) * 3 + (dw + 1)] : 0.0f;
                // OOB taps read ws interior (x0); weight is zeroed.
                x += wv * (float)base[(c * H * W + dh * W + dw) * T];
            }
        }
    }
    xout[gid] = x * tmask;
}

// ---------------- conv phase B: neuron scan over precomputed x --------------
__global__ __launch_bounds__(256) void scan_spike(
    const float* __restrict__ x, uint8_t* __restrict__ out, int rows)
{
    int id = blockIdx.x * 256 + threadIdx.x;
    if (id >= rows) return;
    const float4* xp = (const float4*)(x + (size_t)id * T);
    uchar4* op = (uchar4*)(out + (size_t)id * T);
    float u = 0.f, v = 0.f;
    for (int tb = 0; tb < T / 4; tb++) {
        float4 xv = xp[tb];
        float s0, s1, s2, s3;
        neuron_step(xv.x, u, v, s0); neuron_step(xv.y, u, v, s1);
        neuron_step(xv.z, u, v, s2); neuron_step(xv.w, u, v, s3);
        op[tb] = make_uchar4((unsigned char)s0, (unsigned char)s1,
                             (unsigned char)s2, (unsigned char)s3);
    }
}

// ---------------- FC GEMM: ypart[ks][n][t][o] = sum_c W[o][c]*s5[n][c][t-1] -
// o-tile 128 x t-tile 128 per block, 8x8 per thread, c-split 8, c-chunk 56.
// LDS rows stride 140 with group swizzle -> b128 reads at free 2-way conflicts.
#define FC_CC 56
#define FC_ROW 140
#define FC_CSPLIT 8
#define FC_CRANGE 400

__global__ __launch_bounds__(256) void fc_gemm(
    const uint8_t* __restrict__ s5,   // [16][3200][128]
    const float* __restrict__ fw,     // [512][3200]
    float* __restrict__ ypart)        // [8][16][128][512]
{
    __shared__ float ldsW[FC_CC * FC_ROW];
    __shared__ float ldsS[FC_CC * FC_ROW];

    int bid = blockIdx.x;
    int ks = bid & 7;
    int n  = (bid >> 3) & 15;
    int ob = bid >> 7;                // 0..3
    int o0 = ob * 128;
    int cbase = ks * FC_CRANGE;
    int cend  = cbase + FC_CRANGE;

    int tid = threadIdx.x;
    int og = tid & 15;                // o_local = og*8 + i
    int tg = tid >> 4;                // t = tg*8 + j
    int wo = og * 8 + ((og >> 2) << 2);   // swizzled group offset
    int so = tg * 8 + ((tg >> 2) << 2);

    float acc[8][8];
    #pragma unroll
    for (int i = 0; i < 8; i++)
        #pragma unroll
        for (int j = 0; j < 8; j++) acc[i][j] = 0.f;

    int cW = tid & 63;                // W staging: lane over c (coalesced)
    int oW = tid >> 6;                // 0..3
    int tS = tid & 127;               // S staging: lane over t (coalesced)
    int cS = tid >> 7;                // 0..1

    for (int ch = 0; ch < 8; ch++) {
        int c0 = cbase + ch * FC_CC;
        if (cW < FC_CC) {
            int c = c0 + cW;
            #pragma unroll
            for (int r = 0; r < 32; r++) {
                int oo = oW * 32 + r;
                float wv = (c < cend) ? fw[(o0 + oo) * 3200 + c] : 0.f;
                ldsW[cW * FC_ROW + oo + ((oo >> 5) << 2)] = wv;
            }
        }
        #pragma unroll
        for (int r = 0; r < 28; r++) {
            int cc = cS * 28 + r;
            int c = c0 + cc;
            float sv = 0.f;
            if (tS > 0 && c < cend)
                sv = (float)s5[(n * 3200 + c) * T + tS - 1];   // delay_shift
            ldsS[cc * FC_ROW + tS + ((tS >> 5) << 2)] = sv;
        }
        __syncthreads();
        #pragma unroll 4
        for (int cc = 0; cc < FC_CC; cc++) {
            const float* wr = &ldsW[cc * FC_ROW];
            const float* sr = &ldsS[cc * FC_ROW];
            float4 w0 = *(const float4*)(wr + wo);
            float4 w1 = *(const float4*)(wr + wo + 4);
            float4 sA = *(const float4*)(sr + so);
            float4 sB = *(const float4*)(sr + so + 4);
            float wv[8] = {w0.x, w0.y, w0.z, w0.w, w1.x, w1.y, w1.z, w1.w};
            float sv[8] = {sA.x, sA.y, sA.z, sA.w, sB.x, sB.y, sB.z, sB.w};
            #pragma unroll
            for (int i = 0; i < 8; i++)
                #pragma unroll
                for (int j = 0; j < 8; j++)
                    acc[i][j] += wv[i] * sv[j];
        }
        __syncthreads();
    }

    float* yp = ypart + ((ks * 16 + n) * T) * 512;
    #pragma unroll
    for (int j = 0; j < 8; j++) {
        int t = tg * 8 + j;
        float4 v0 = make_float4(acc[0][j], acc[1][j], acc[2][j], acc[3][j]);
        float4 v1 = make_float4(acc[4][j], acc[5][j], acc[6][j], acc[7][j]);
        *(float4*)&yp[t * 512 + o0 + og * 8]     = v0;
        *(float4*)&yp[t * 512 + o0 + og * 8 + 4] = v1;
    }
}

// ---------------- FC partial reduce + neuron scan + output delay ------------
__global__ __launch_bounds__(256) void fc_reduce(
    const float* __restrict__ yp, float* __restrict__ ys)
{
    int id = blockIdx.x * 256 + threadIdx.x;          // 1,048,576
    float x = 0.f;
    #pragma unroll
    for (int k = 0; k < 8; k++) x += yp[k * 1048576 + id];
    ys[id] = x;
}

__global__ __launch_bounds__(256) void fc_scan(
    const float* __restrict__ ysum,   // [16][128][512]
    float* __restrict__ out)          // [16][512][128]
{
    int id = blockIdx.x * 256 + threadIdx.x;          // 8192
    int o = id & 511;
    int n = id >> 9;
    float u = 0.f, v = 0.f;
    float prev = 0.f;                 // final delay_shift
    for (int t = 0; t < T; t++) {
        float x = ysum[(n * T + t) * 512 + o];
        float s;
        neuron_step(x, u, v, s);
        out[(n * 512 + o) * T + t] = prev;
        prev = s;
    }
}

// ---------------- launch ----------------------------------------------------
extern "C" void kernel_launch(void* const* d_in, const int* in_sizes, int n_in,
                              void* d_out, int out_size, void* d_ws, size_t ws_size,
                              hipStream_t stream) {
    const float* spike = (const float*)d_in[0];   // [16][2][40][40][128]
    const float* c1w   = (const float*)d_in[1];   // [8][2][3][3]
    const float* c2w   = (const float*)d_in[2];   // [16][8][3][3]
    const float* c3w   = (const float*)d_in[3];   // [32][16][3][3]
    const float* p1w   = (const float*)d_in[4];   // scalar
    const float* p2w   = (const float*)d_in[5];   // scalar
    const float* fcw   = (const float*)d_in[6];   // [512][3200]
    float* out = (float*)d_out;                   // [16][512][128]

    char* ws = (char*)d_ws;
    // ws layout (bytes): total need = 108,134,400
    uint8_t* s1 = (uint8_t*)(ws);                 // 26,214,400
    uint8_t* s2 = (uint8_t*)(ws + 26214400);      //  6,553,600
    uint8_t* s3 = (uint8_t*)(ws + 32768000);      // 13,107,200
    uint8_t* s4 = (uint8_t*)(ws + 45875200);      //  3,276,800
    uint8_t* s5 = (uint8_t*)(ws + 49152000);      //  6,553,600
    float* xbuf  = (float*)(ws + 55705600);       // 52,428,800 (conv2/conv3 x)
    float* ypart = (float*)(ws + 55705600);       // 33,554,432 (aliases xbuf)
    float* ysumb = (float*)(ws + 55705600 + 33554432); // 4,194,304

    conv1_spike<<<800, 256, 0, stream>>>(spike, c1w, s1);
    pool_spike<8, 20, 20><<<200, 256, 0, stream>>>(s1, p1w, s2);
    conv_x<8, 20, 20><<<51200, 256, 0, stream>>>(s2, c2w, 100.0f, xbuf, 16);
    scan_spike<<<400, 256, 0, stream>>>(xbuf, s3, 102400);
    pool_spike<16, 10, 10><<<100, 256, 0, stream>>>(s3, p2w, s4);
    conv_x<16, 10, 10><<<25600, 256, 0, stream>>>(s4, c3w, 100.0f, xbuf, 32);
    scan_spike<<<200, 256, 0, stream>>>(xbuf, s5, 51200);
    fc_gemm<<<512, 256, 0, stream>>>(s5, fcw, ypart);
    fc_reduce<<<4096, 256, 0, stream>>>(ypart, ysumb);
    fc_scan<<<32, 256, 0, stream>>>(ysumb, out);
}

// Round 2
// 782.972 us; speedup vs baseline: 1.5820x; 1.5820x over previous
//
#include <hip/hip_runtime.h>
#include <stdint.h>

// SNN forward: conv1+spike -> pool1+spike -> conv2+spike -> pool2+spike ->
// conv3+spike -> fc+spike, each with delay_shift between layers.
// Neuron: u = 0.75u + x; v = 0.96875v + u; s = (v>=100); v *= (1-s).
// Intermediate spikes as uint8 in d_ws.

#define T 128
#define AI 0.75f
#define AV 0.96875f
#define THETA 100.0f

__device__ __forceinline__ void neuron_step(float x, float& u, float& v, float& s) {
    u = AI * u + x;
    v = AV * v + u;
    s = (v >= THETA) ? 1.0f : 0.0f;
    v = v * (1.0f - s);
}

// ---------------- conv1 phase A: x[n][o][h][w][t], lanes over t -------------
// in: [16][2][40][40][128] float, w: [8][2][3][3] (x20)
// Thread = (n,h,w,t); o-loop internal (18 coalesced loads amortize 144 fma).
__global__ __launch_bounds__(256) void conv1_x(
    const float* __restrict__ in, const float* __restrict__ cw,
    float* __restrict__ xout)
{
    __shared__ float wsm[144];
    if (threadIdx.x < 144) wsm[threadIdx.x] = cw[threadIdx.x] * 20.0f;
    __syncthreads();

    int gid = blockIdx.x * 256 + threadIdx.x;   // 3,276,800 total
    int t  = gid & 127;
    int hw = gid >> 7;
    int wx = hw % 40;
    int hy = (hw / 40) % 40;
    int n  = hw / 1600;

    float val[18];
    #pragma unroll
    for (int c = 0; c < 2; c++)
      #pragma unroll
      for (int dh = -1; dh <= 1; dh++)
        #pragma unroll
        for (int dw = -1; dw <= 1; dw++) {
            int q = c * 9 + (dh + 1) * 3 + (dw + 1);
            int hh = hy + dh, ww = wx + dw;
            bool ok = (hh >= 0) && (hh < 40) && (ww >= 0) && (ww < 40);
            val[q] = ok ? in[(((n * 2 + c) * 40 + hh) * 40 + ww) * T + t] : 0.0f;
        }

    #pragma unroll
    for (int o = 0; o < 8; o++) {
        float x = 0.f;
        #pragma unroll
        for (int q = 0; q < 18; q++) x += wsm[o * 18 + q] * val[q];
        xout[(((n * 8 + o) * 40 + hy) * 40 + wx) * T + t] = x;
    }
}

// ---------------- sum-pool 2x2 (*pw) on DELAYED spikes, fused scan ----------
// in: [16][C][2HO][2WO][T] u8, out: [16][C][HO][WO][T] u8
template<int C, int HO, int WO>
__global__ __launch_bounds__(256) void pool_spike(
    const uint8_t* __restrict__ in, const float* __restrict__ pw_ptr,
    uint8_t* __restrict__ out)
{
    int id = blockIdx.x * 256 + threadIdx.x;          // N*C*HO*WO
    int wx = id % WO;
    int hy = (id / WO) % HO;
    int c  = (id / (WO * HO)) % C;
    int n  = id / (WO * HO * C);
    float pw = pw_ptr[0];

    const uint8_t* p00 = in + (((n * C + c) * (2 * HO) + 2 * hy) * (2 * WO) + 2 * wx) * T;
    const uint8_t* p01 = p00 + T;
    const uint8_t* p10 = p00 + 2 * WO * T;
    const uint8_t* p11 = p10 + T;
    uint8_t* op = out + (((n * C + c) * HO + hy) * WO + wx) * T;

    float u = 0.f, v = 0.f;
    int prev = 0;  // pooled sum at t-1 (delay_shift)
    for (int tb = 0; tb < T / 4; tb++) {
        uchar4 a = *(const uchar4*)(p00 + tb * 4);
        uchar4 b = *(const uchar4*)(p01 + tb * 4);
        uchar4 cc = *(const uchar4*)(p10 + tb * 4);
        uchar4 d = *(const uchar4*)(p11 + tb * 4);
        int s1i = a.x + b.x + cc.x + d.x;
        int s2i = a.y + b.y + cc.y + d.y;
        int s3i = a.z + b.z + cc.z + d.z;
        float s0, s1, s2, s3;
        neuron_step(pw * (float)prev, u, v, s0);
        neuron_step(pw * (float)s1i,  u, v, s1);
        neuron_step(pw * (float)s2i,  u, v, s2);
        neuron_step(pw * (float)s3i,  u, v, s3);
        prev = a.w + b.w + cc.w + d.w;
        *(uchar4*)(op + tb * 4) =
            make_uchar4((unsigned char)s0, (unsigned char)s1,
                        (unsigned char)s2, (unsigned char)s3);
    }
}

// ---------------- conv phase A: x[n][o][h][w][t] from DELAYED u8 spikes -----
// Fully parallel over (n,o,h,w,t). 256 | W*T*H guarantees per-block uniform o.
template<int CIN, int H, int W>
__global__ __launch_bounds__(256) void conv_x(
    const uint8_t* __restrict__ in, const float* __restrict__ cw, float scale,
    float* __restrict__ xout, int COUT)
{
    __shared__ float wsm[CIN * 9];
    int gid = blockIdx.x * 256 + threadIdx.x;
    int t  = gid % T;
    int wx = (gid / T) % W;
    int hy = (gid / (T * W)) % H;
    int o  = (gid / (T * W * H)) % COUT;
    int n  = gid / (T * W * H * COUT);
    if (threadIdx.x < CIN * 9) wsm[threadIdx.x] = cw[o * CIN * 9 + threadIdx.x] * scale;
    __syncthreads();

    int tm = (t == 0) ? 0 : (t - 1);                  // delay_shift
    float tmask = (t == 0) ? 0.0f : 1.0f;
    const uint8_t* base = in + ((n * CIN * H + hy) * W + wx) * T + tm;

    float x = 0.f;
    #pragma unroll
    for (int c = 0; c < CIN; c++) {
        #pragma unroll
        for (int dh = -1; dh <= 1; dh++) {
            #pragma unroll
            for (int dw = -1; dw <= 1; dw++) {
                bool ok = (hy + dh >= 0) && (hy + dh < H) &&
                          (wx + dw >= 0) && (wx + dw < W);
                float wv = ok ? wsm[c * 9 + (dh + 1) * 3 + (dw + 1)] : 0.0f;
                // OOB taps read ws interior (x0); weight is zeroed.
                x += wv * (float)base[(c * H * W + dh * W + dw) * T];
            }
        }
    }
    xout[gid] = x * tmask;
}

// ---------------- conv phase B: neuron scan over precomputed x --------------
__global__ __launch_bounds__(256) void scan_spike(
    const float* __restrict__ x, uint8_t* __restrict__ out, int rows)
{
    int id = blockIdx.x * 256 + threadIdx.x;
    if (id >= rows) return;
    const float4* xp = (const float4*)(x + (size_t)id * T);
    uchar4* op = (uchar4*)(out + (size_t)id * T);
    float u = 0.f, v = 0.f;
    for (int tb = 0; tb < T / 4; tb++) {
        float4 xv = xp[tb];
        float s0, s1, s2, s3;
        neuron_step(xv.x, u, v, s0); neuron_step(xv.y, u, v, s1);
        neuron_step(xv.z, u, v, s2); neuron_step(xv.w, u, v, s3);
        op[tb] = make_uchar4((unsigned char)s0, (unsigned char)s1,
                             (unsigned char)s2, (unsigned char)s3);
    }
}

// ---------------- FC GEMM: ypart[ks][n][t][o] = sum_c W[o][c]*s5[n][c][t-1] -
// o-tile 128 x t-tile 128 per block, 8x8 per thread, c-split 8, c-chunk 56.
// LDS rows stride 140 with group swizzle -> b128 reads at free 2-way conflicts.
#define FC_CC 56
#define FC_ROW 140
#define FC_CSPLIT 8
#define FC_CRANGE 400

__global__ __launch_bounds__(256) void fc_gemm(
    const uint8_t* __restrict__ s5,   // [16][3200][128]
    const float* __restrict__ fw,     // [512][3200]
    float* __restrict__ ypart)        // [8][16][128][512]
{
    __shared__ float ldsW[FC_CC * FC_ROW];
    __shared__ float ldsS[FC_CC * FC_ROW];

    int bid = blockIdx.x;
    int ks = bid & 7;
    int n  = (bid >> 3) & 15;
    int ob = bid >> 7;                // 0..3
    int o0 = ob * 128;
    int cbase = ks * FC_CRANGE;
    int cend  = cbase + FC_CRANGE;

    int tid = threadIdx.x;
    int og = tid & 15;                // o_local = og*8 + i
    int tg = tid >> 4;                // t = tg*8 + j
    int wo = og * 8 + ((og >> 2) << 2);   // swizzled group offset
    int so = tg * 8 + ((tg >> 2) << 2);

    float acc[8][8];
    #pragma unroll
    for (int i = 0; i < 8; i++)
        #pragma unroll
        for (int j = 0; j < 8; j++) acc[i][j] = 0.f;

    int cW = tid & 63;                // W staging: lane over c (coalesced)
    int oW = tid >> 6;                // 0..3
    int tS = tid & 127;               // S staging: lane over t (coalesced)
    int cS = tid >> 7;                // 0..1

    for (int ch = 0; ch < 8; ch++) {
        int c0 = cbase + ch * FC_CC;
        if (cW < FC_CC) {
            int c = c0 + cW;
            #pragma unroll
            for (int r = 0; r < 32; r++) {
                int oo = oW * 32 + r;
                float wv = (c < cend) ? fw[(o0 + oo) * 3200 + c] : 0.f;
                ldsW[cW * FC_ROW + oo + ((oo >> 5) << 2)] = wv;
            }
        }
        #pragma unroll
        for (int r = 0; r < 28; r++) {
            int cc = cS * 28 + r;
            int c = c0 + cc;
            float sv = 0.f;
            if (tS > 0 && c < cend)
                sv = (float)s5[(n * 3200 + c) * T + tS - 1];   // delay_shift
            ldsS[cc * FC_ROW + tS + ((tS >> 5) << 2)] = sv;
        }
        __syncthreads();
        #pragma unroll 4
        for (int cc = 0; cc < FC_CC; cc++) {
            const float* wr = &ldsW[cc * FC_ROW];
            const float* sr = &ldsS[cc * FC_ROW];
            float4 w0 = *(const float4*)(wr + wo);
            float4 w1 = *(const float4*)(wr + wo + 4);
            float4 sA = *(const float4*)(sr + so);
            float4 sB = *(const float4*)(sr + so + 4);
            float wv[8] = {w0.x, w0.y, w0.z, w0.w, w1.x, w1.y, w1.z, w1.w};
            float sv[8] = {sA.x, sA.y, sA.z, sA.w, sB.x, sB.y, sB.z, sB.w};
            #pragma unroll
            for (int i = 0; i < 8; i++)
                #pragma unroll
                for (int j = 0; j < 8; j++)
                    acc[i][j] += wv[i] * sv[j];
        }
        __syncthreads();
    }

    float* yp = ypart + ((ks * 16 + n) * T) * 512;
    #pragma unroll
    for (int j = 0; j < 8; j++) {
        int t = tg * 8 + j;
        float4 v0 = make_float4(acc[0][j], acc[1][j], acc[2][j], acc[3][j]);
        float4 v1 = make_float4(acc[4][j], acc[5][j], acc[6][j], acc[7][j]);
        *(float4*)&yp[t * 512 + o0 + og * 8]     = v0;
        *(float4*)&yp[t * 512 + o0 + og * 8 + 4] = v1;
    }
}

// ---------------- FC partial reduce + neuron scan + output delay ------------
__global__ __launch_bounds__(256) void fc_reduce(
    const float* __restrict__ yp, float* __restrict__ ys)
{
    int id = blockIdx.x * 256 + threadIdx.x;          // 1,048,576
    float x = 0.f;
    #pragma unroll
    for (int k = 0; k < 8; k++) x += yp[k * 1048576 + id];
    ys[id] = x;
}

__global__ __launch_bounds__(256) void fc_scan(
    const float* __restrict__ ysum,   // [16][128][512]
    float* __restrict__ out)          // [16][512][128]
{
    int id = blockIdx.x * 256 + threadIdx.x;          // 8192
    int o = id & 511;
    int n = id >> 9;
    float u = 0.f, v = 0.f;
    float prev = 0.f;                 // final delay_shift
    for (int t = 0; t < T; t++) {
        float x = ysum[(n * T + t) * 512 + o];
        float s;
        neuron_step(x, u, v, s);
        out[(n * 512 + o) * T + t] = prev;
        prev = s;
    }
}

// ---------------- launch ----------------------------------------------------
extern "C" void kernel_launch(void* const* d_in, const int* in_sizes, int n_in,
                              void* d_out, int out_size, void* d_ws, size_t ws_size,
                              hipStream_t stream) {
    const float* spike = (const float*)d_in[0];   // [16][2][40][40][128]
    const float* c1w   = (const float*)d_in[1];   // [8][2][3][3]
    const float* c2w   = (const float*)d_in[2];   // [16][8][3][3]
    const float* c3w   = (const float*)d_in[3];   // [32][16][3][3]
    const float* p1w   = (const float*)d_in[4];   // scalar
    const float* p2w   = (const float*)d_in[5];   // scalar
    const float* fcw   = (const float*)d_in[6];   // [512][3200]
    float* out = (float*)d_out;                   // [16][512][128]

    char* ws = (char*)d_ws;
    // ws layout (bytes):
    uint8_t* s1 = (uint8_t*)(ws);                 // 26,214,400
    uint8_t* s2 = (uint8_t*)(ws + 26214400);      //  6,553,600
    uint8_t* s3 = (uint8_t*)(ws + 32768000);      // 13,107,200
    uint8_t* s4 = (uint8_t*)(ws + 45875200);      //  3,276,800
    uint8_t* s5 = (uint8_t*)(ws + 49152000);      //  6,553,600
    float* xbuf  = (float*)(ws + 55705600);       // 52,428,800 (conv2/conv3 x)
    float* ypart = (float*)(ws + 55705600);       // 33,554,432 (aliases xbuf)
    float* ysumb = (float*)(ws + 55705600 + 33554432); // 4,194,304
    float* xbuf1 = (float*)(ws + 93454336);       // 104,857,600 (conv1 x)
    // total: 198,311,936 bytes

    conv1_x<<<12800, 256, 0, stream>>>(spike, c1w, xbuf1);
    scan_spike<<<800, 256, 0, stream>>>(xbuf1, s1, 204800);
    pool_spike<8, 20, 20><<<200, 256, 0, stream>>>(s1, p1w, s2);
    conv_x<8, 20, 20><<<51200, 256, 0, stream>>>(s2, c2w, 100.0f, xbuf, 16);
    scan_spike<<<400, 256, 0, stream>>>(xbuf, s3, 102400);
    pool_spike<16, 10, 10><<<100, 256, 0, stream>>>(s3, p2w, s4);
    conv_x<16, 10, 10><<<25600, 256, 0, stream>>>(s4, c3w, 100.0f, xbuf, 32);
    scan_spike<<<200, 256, 0, stream>>>(xbuf, s5, 51200);
    fc_gemm<<<512, 256, 0, stream>>>(s5, fcw, ypart);
    fc_reduce<<<4096, 256, 0, stream>>>(ypart, ysumb);
    fc_scan<<<32, 256, 0, stream>>>(ysumb, out);
}